// Round 9
// baseline (361.650 us; speedup 1.0000x reference)
//
#include <hip/hip_runtime.h>

// Polar encoder: N=1024, K=512, BATCH=65536.
// R9: algebraic shortcut. The stage loop computes out_j = XOR_{i superset j} x_i.
// With frozen = [0,512) and info = [512,1024) (reference's setup), x is zero on
// the low half, so out[j] = F9(u)[j mod 512]: the 9-stage butterfly of the 512
// info bits, DUPLICATED into both halves. One wave = one row, no LDS, no inv,
// no ballots: lane l packs u[8l..8l+7] into a byte, 3 in-byte stages + 6-stage
// 64-lane shfl_xor butterfly, expand via 2 shfls, 4 NT float4 stores.
// Grid-uniform guard falls back to the generic (R8-verified) path.

#define PN     1024
#define PK     512
#define PBATCH 65536

typedef float vf4 __attribute__((ext_vector_type(4)));

__global__ __launch_bounds__(256) void polar_encode_kernel(
    const float* __restrict__ u,
    const int*   __restrict__ info_pos,
    vf4*         __restrict__ out4)
{
    // fallback scratch (unused on fast path; 12 KB/block, not occupancy-limiting)
    __shared__ int   inv[PN];
    __shared__ float su[4][PK];

    const int tid  = threadIdx.x;
    const int lane = tid & 63;
    const int wave = tid >> 6;
    const unsigned row  = blockIdx.x * 4u + wave;
    const unsigned base = row * (PN / 4);          // float4 base of this row

    // grid-uniform structure check: info_pos sorted unique in [0,1024);
    // endpoints 512 & 1023 with 512 entries  =>  info_pos == [512..1023]
    const bool fast = (info_pos[0] == PK) && (info_pos[PK - 1] == PN - 1);

    if (fast) {
        // ---- pack: lane l holds byte l of the 512-bit info vector
        const float4* u4 = (const float4*)(u + (size_t)row * PK);
        const float4 a = u4[2 * lane];
        const float4 b = u4[2 * lane + 1];
        unsigned int byte =
            ((unsigned)a.x)        | ((unsigned)a.y << 1) |
            ((unsigned)a.z << 2)   | ((unsigned)a.w << 3) |
            ((unsigned)b.x << 4)   | ((unsigned)b.y << 5) |
            ((unsigned)b.z << 6)   | ((unsigned)b.w << 7);

        // ---- 9-stage butterfly on 512 bits
        // stages 0..2: in-byte (bit distance 1,2,4)
        byte ^= (byte >> 1) & 0x55u;
        byte ^= (byte >> 2) & 0x33u;
        byte ^= (byte >> 4) & 0x0Fu;
        // stages 3..8: cross-lane (byte distance 1..32)
        #pragma unroll
        for (int off = 1; off <= 32; off <<= 1) {
            const unsigned int p =
                (unsigned int)__shfl_xor((int)byte, off, 64);
            if ((lane & off) == 0) byte ^= p;
        }

        // ---- expand (output = half duplicated twice): float4 f needs byte
        // ((f mod 128)>>1); for f=j*64+lane that's (j&1)*32 + (lane>>1).
        const unsigned int bEven =
            (unsigned int)__shfl((int)byte, lane >> 1, 64);
        const unsigned int bOdd =
            (unsigned int)__shfl((int)byte, 32 + (lane >> 1), 64);
        const unsigned int sh   = (lane & 1) * 4;       // nibble select
        const unsigned int nibE = (bEven >> sh) & 0xFu;
        const unsigned int nibO = (bOdd  >> sh) & 0xFu;

        #pragma unroll
        for (int j = 0; j < 4; ++j) {
            const unsigned int nib = (j & 1) ? nibO : nibE;
            vf4 v;
            v.x = (nib & 1u) ? 1.0f : 0.0f;
            v.y = (nib & 2u) ? 1.0f : 0.0f;
            v.z = (nib & 4u) ? 1.0f : 0.0f;
            v.w = (nib & 8u) ? 1.0f : 0.0f;
            __builtin_nontemporal_store(v, out4 + base + j * 64 + lane);
        }
        return;
    }

    // ---------------- generic fallback (R8-verified path) ----------------
    #pragma unroll
    for (int i = tid; i < PN; i += 256) inv[i] = -1;
    __syncthreads();
    #pragma unroll
    for (int k = tid; k < PK; k += 256) inv[info_pos[k]] = k;
    __syncthreads();

    float* srow = su[wave];
    {
        const float4* u4 = (const float4*)(u + (size_t)row * PK);
        const float4 a0 = u4[lane];
        const float4 a1 = u4[64 + lane];
        float4* s4 = (float4*)srow;
        s4[lane]      = a0;
        s4[64 + lane] = a1;
    }
    const int l31 = lane & 31;
    unsigned int word = 0;
    #pragma unroll
    for (int c = 0; c < PN / 64; ++c) {
        const int   iv  = inv[c * 64 + lane];
        const float v   = srow[iv & (PK - 1)];
        const bool  bit = (iv >= 0) && (v != 0.0f);
        const unsigned long long m = __ballot(bit);
        const unsigned int sel =
            (l31 & 1) ? (unsigned int)(m >> 32) : (unsigned int)m;
        if ((l31 >> 1) == c) word = sel;
    }
    word ^= (word >> 1)  & 0x55555555u;
    word ^= (word >> 2)  & 0x33333333u;
    word ^= (word >> 4)  & 0x0F0F0F0Fu;
    word ^= (word >> 8)  & 0x00FF00FFu;
    word ^= (word >> 16) & 0x0000FFFFu;
    #pragma unroll
    for (int off = 1; off <= 16; off <<= 1) {
        const unsigned int partner =
            (unsigned int)__shfl_xor((int)word, off, 64);
        if ((l31 & off) == 0) word ^= partner;
    }
    #pragma unroll
    for (int j = 0; j < 4; ++j) {
        const int f   = j * 64 + lane;
        const int src = f >> 3;
        const unsigned int b   = (unsigned int)__shfl((int)word, src, 64);
        const unsigned int nib = (b >> ((f & 7) * 4)) & 0xFu;
        vf4 v;
        v.x = (nib & 1u) ? 1.0f : 0.0f;
        v.y = (nib & 2u) ? 1.0f : 0.0f;
        v.z = (nib & 4u) ? 1.0f : 0.0f;
        v.w = (nib & 8u) ? 1.0f : 0.0f;
        __builtin_nontemporal_store(v, out4 + base + f);
    }
}

extern "C" void kernel_launch(void* const* d_in, const int* in_sizes, int n_in,
                              void* d_out, int out_size, void* d_ws, size_t ws_size,
                              hipStream_t stream) {
    const float* u        = (const float*)d_in[0];
    const int*   info_pos = (const int*)d_in[1];
    vf4* out4 = (vf4*)d_out;

    polar_encode_kernel<<<PBATCH / 4, 256, 0, stream>>>(u, info_pos, out4);
}